// Round 7
// baseline (181.084 us; speedup 1.0000x reference)
//
#include <hip/hip_runtime.h>
#include <hip/hip_bf16.h>

#define N_ITEMS 8192
#define DIM 64
#define BATCH 4096
#define NCLASS 50
#define JS 8                           // grid.y j-splits
#define WPB 4                          // waves per block
#define JR (N_ITEMS / (JS * WPB))      // 256 j-rows per wave
#define NTILES (JR / 32)               // 8 tiles of 32 j-rows
#define TOTAL_BLOCKS (128 * JS)        // 1024
#define INV_T (1.0f / 0.07f)
#define LOG2E 1.4426950408889634f

typedef __bf16 bf16_t;
typedef __attribute__((ext_vector_type(8))) __bf16 bf16x8;
typedef __attribute__((ext_vector_type(16))) float f32x16;

#if __has_builtin(__builtin_amdgcn_exp2f)
#define EXP2(x) __builtin_amdgcn_exp2f(x)
#else
#define EXP2(x) __expf((x) * 0.6931471805599453f)
#endif

__device__ __forceinline__ float wave_sum(float v) {
    #pragma unroll
    for (int off = 32; off; off >>= 1) v += __shfl_xor(v, off, 64);
    return v;
}

// Prep: normalize rows -> bf16 featB, zero S/done/loss; plus rating head.
// Blocks [0,2048): normalize, 4 rows each. Blocks [2048,3072): rating.
__global__ __launch_bounds__(256) void prep_rating(
    const float* __restrict__ emb, const int* __restrict__ idx,
    const float* __restrict__ aw, const float* __restrict__ ab,
    bf16_t* __restrict__ featB, float* __restrict__ S,
    unsigned int* __restrict__ done, float* __restrict__ out) {
    int t = threadIdx.x, lane = t & 63, w = t >> 6;
    int bid = blockIdx.x;
    if (bid < N_ITEMS / 4) {
        int row = bid * 4 + w;
        float x = emb[row * DIM + lane];
        float ss = wave_sum(x * x);
        float f = x * __frsqrt_rn(fmaxf(ss, 1e-24f));
        featB[row * DIM + lane] = (bf16_t)f;
        if (lane == 0) S[row] = 0.f;
        if (bid == 0 && t == 0) { out[BATCH] = 0.f; *done = 0u; }
    } else {
        int row = (bid - N_ITEMS / 4) * 4 + w;
        int it = idx[row];
        float x = emb[it * DIM + lane] * aw[lane];
        x = wave_sum(x);
        if (lane == 0) out[row] = 1.0f / (1.0f + __expf(-(x + ab[0])));
    }
}

// Phase B: MFMA Gram + fused exp-sum into S (m_i == 1/T analytically).
// Then completion-counter; blocks (bx<50, by==0) wait and run per-class
// finalize:
//   sum_{i in c} feat_i . g_c = |g_c|^2
//   term_c = (|g_c|^2/T - (1+C)*cnt/T - C*lsum) / (C+1e-6), 0 if C < 1
//   loss  -= term_c / N      (50 atomics total)
__global__ __launch_bounds__(256) void supcon_fin(
    const bf16_t* __restrict__ featB, const int* __restrict__ labels,
    float* __restrict__ S, unsigned int* __restrict__ done,
    float* __restrict__ out) {
    __shared__ float sg[4][DIM];
    __shared__ float sl[4], sc4[4];
    const float scale = INV_T * LOG2E;
    const float bias = -INV_T * LOG2E;
    int t = threadIdx.x;
    int lane = t & 63;
    int wv = t >> 6;
    int col = lane & 31;
    int half = lane >> 5;
    int i0 = blockIdx.x * 64;
    int ig0 = i0 + col, ig1 = i0 + 32 + col;

    // B frags for the two i-groups (identical addressing to A — Gram matrix)
    bf16x8 bf0[4], bf1[4];
    const bf16_t* b0p = featB + (size_t)ig0 * DIM + half * 8;
    const bf16_t* b1p = featB + (size_t)ig1 * DIM + half * 8;
    #pragma unroll
    for (int s = 0; s < 4; ++s) {
        bf0[s] = *reinterpret_cast<const bf16x8*>(b0p + s * 16);
        bf1[s] = *reinterpret_cast<const bf16x8*>(b1p + s * 16);
    }

    int jbase = (blockIdx.y * WPB + wv) * JR;
    int rowoff = half * 4;
    float p0[4] = {0.f, 0.f, 0.f, 0.f}, p1[4] = {0.f, 0.f, 0.f, 0.f};

    for (int tile = 0; tile < NTILES; ++tile) {
        int jt = jbase + tile * 32;
        const bf16_t* arowp = featB + (size_t)(jt + col) * DIM + half * 8;
        f32x16 c0 = {}, c1 = {};
        #pragma unroll
        for (int s = 0; s < 4; ++s) {
            bf16x8 a = *reinterpret_cast<const bf16x8*>(arowp + s * 16);
            c0 = __builtin_amdgcn_mfma_f32_32x32x16_bf16(a, bf0[s], c0, 0, 0, 0);
            c1 = __builtin_amdgcn_mfma_f32_32x32x16_bf16(a, bf1[s], c1, 0, 0, 0);
        }
        if (jt != i0) {
            #pragma unroll
            for (int r = 0; r < 16; ++r)
                p0[r & 3] += EXP2(fmaf(c0[r], scale, bias));
        } else {
            #pragma unroll
            for (int r = 0; r < 16; ++r) {
                int jrow = (r & 3) + 8 * (r >> 2) + rowoff;
                float e = EXP2(fmaf(c0[r], scale, bias));
                p0[r & 3] += (jrow != col) ? e : 0.f;
            }
        }
        if (jt != i0 + 32) {
            #pragma unroll
            for (int r = 0; r < 16; ++r)
                p1[r & 3] += EXP2(fmaf(c1[r], scale, bias));
        } else {
            #pragma unroll
            for (int r = 0; r < 16; ++r) {
                int jrow = (r & 3) + 8 * (r >> 2) + rowoff;
                float e = EXP2(fmaf(c1[r], scale, bias));
                p1[r & 3] += (jrow != col) ? e : 0.f;
            }
        }
    }
    float a0 = (p0[0] + p0[1]) + (p0[2] + p0[3]);
    float a1 = (p1[0] + p1[1]) + (p1[2] + p1[3]);
    a0 += __shfl_xor(a0, 32, 64);
    a1 += __shfl_xor(a1, 32, 64);
    if (lane < 32) {
        unsafeAtomicAdd(&S[ig0], a0);
        unsafeAtomicAdd(&S[ig1], a1);
    }

    // ---- completion counter (canonical threadfence + syncthreads + inc) ----
    __threadfence();
    __syncthreads();
    if (t == 0) atomicAdd(done, 1u);
    if (blockIdx.y != 0 || blockIdx.x >= NCLASS) return;

    if (t == 0) {
        while (__hip_atomic_load(done, __ATOMIC_ACQUIRE,
                                 __HIP_MEMORY_SCOPE_AGENT) < TOTAL_BLOCKS)
            __builtin_amdgcn_s_sleep(8);
    }
    __syncthreads();
    __threadfence();

    // ---- per-class finalize, class c = blockIdx.x ----
    {
        int c = blockIdx.x;
        float gacc = 0.f, lacc = 0.f, cacc = 0.f;
        for (int strip = wv; strip < N_ITEMS / 64; strip += 4) {
            int r = strip * 64 + lane;
            bool match = (labels[r] == c);
            unsigned long long mask = __ballot(match);
            if (match) {
                float sv = __hip_atomic_load(&S[r], __ATOMIC_RELAXED,
                                             __HIP_MEMORY_SCOPE_AGENT);
                lacc += __logf(sv + 1e-6f);
                cacc += 1.f;
            }
            const bf16_t* base = featB + (size_t)strip * 64 * DIM + lane;
            while (mask) {
                int bit = __builtin_ctzll(mask);
                mask &= mask - 1;
                gacc += (float)base[bit * DIM];
            }
        }
        lacc = wave_sum(lacc);
        cacc = wave_sum(cacc);
        sg[wv][lane] = gacc;
        if (lane == 0) { sl[wv] = lacc; sc4[wv] = cacc; }
        __syncthreads();
        if (wv == 0) {
            float g = (sg[0][lane] + sg[1][lane]) + (sg[2][lane] + sg[3][lane]);
            float dot = wave_sum(g * g);
            if (lane == 0) {
                float cnt = (sc4[0] + sc4[1]) + (sc4[2] + sc4[3]);
                float ls  = (sl[0] + sl[1]) + (sl[2] + sl[3]);
                float C = cnt - 1.f;
                float term = (C > 0.5f)
                    ? (dot * INV_T - (1.f + C) * cnt * INV_T - C * ls) / (C + 1e-6f)
                    : 0.f;
                unsafeAtomicAdd(&out[BATCH], -term / (float)N_ITEMS);
            }
        }
    }
}

extern "C" void kernel_launch(void* const* d_in, const int* in_sizes, int n_in,
                              void* d_out, int out_size, void* d_ws, size_t ws_size,
                              hipStream_t stream) {
    const int*   item_indices = (const int*)d_in[0];
    const int*   labels       = (const int*)d_in[1];
    const float* emb          = (const float*)d_in[2];
    const float* aw           = (const float*)d_in[3];
    const float* ab           = (const float*)d_in[4];
    float* out = (float*)d_out;   // [4096 ratings][1 supcon]

    bf16_t*       featB = (bf16_t*)d_ws;                     // 8192*64 bf16 (1 MB)
    float*        S     = (float*)(featB + N_ITEMS * DIM);   // 8192
    unsigned int* done  = (unsigned int*)(S + N_ITEMS);      // 1

    prep_rating<<<N_ITEMS / 4 + BATCH / 4, 256, 0, stream>>>(
        emb, item_indices, aw, ab, featB, S, done, out);

    dim3 grid(N_ITEMS / 64, JS);
    supcon_fin<<<grid, 256, 0, stream>>>(featB, labels, S, done, out);
}

// Round 8
// 102.234 us; speedup vs baseline: 1.7713x; 1.7713x over previous
//
#include <hip/hip_runtime.h>
#include <hip/hip_bf16.h>

#define N_ITEMS 8192
#define DIM 64
#define BATCH 4096
#define NCLASS 50
#define JS 8                           // j-splits
#define WPB 4                          // waves per block
#define JR (N_ITEMS / (JS * WPB))      // 256 j-rows per wave
#define NTILES (JR / 32)               // 8 tiles of 32 j-rows
#define GRAM_BLOCKS (128 * JS)         // 1024 MFMA blocks; +NCLASS gather blocks
#define INV_T (1.0f / 0.07f)
#define LOG2E 1.4426950408889634f

typedef __bf16 bf16_t;
typedef __attribute__((ext_vector_type(8))) __bf16 bf16x8;
typedef __attribute__((ext_vector_type(16))) float f32x16;

#if __has_builtin(__builtin_amdgcn_exp2f)
#define EXP2(x) __builtin_amdgcn_exp2f(x)
#else
#define EXP2(x) __expf((x) * 0.6931471805599453f)
#endif

__device__ __forceinline__ float wave_sum(float v) {
    #pragma unroll
    for (int off = 32; off; off >>= 1) v += __shfl_xor(v, off, 64);
    return v;
}

// Prep: normalize rows -> bf16 featB, zero S + loss slot; rating head. No atomics.
// Blocks [0,2048): normalize, 4 rows each. Blocks [2048,3072): rating.
__global__ __launch_bounds__(256) void prep_rating(
    const float* __restrict__ emb, const int* __restrict__ idx,
    const float* __restrict__ aw, const float* __restrict__ ab,
    bf16_t* __restrict__ featB, float* __restrict__ S,
    float* __restrict__ out) {
    int t = threadIdx.x, lane = t & 63, w = t >> 6;
    int bid = blockIdx.x;
    if (bid < N_ITEMS / 4) {
        int row = bid * 4 + w;
        float x = emb[row * DIM + lane];
        float ss = wave_sum(x * x);
        float f = x * __frsqrt_rn(fmaxf(ss, 1e-24f));
        featB[row * DIM + lane] = (bf16_t)f;
        if (lane == 0) S[row] = 0.f;
        if (bid == 0 && t == 0) out[BATCH] = 0.f;
    } else {
        int row = (bid - N_ITEMS / 4) * 4 + w;
        int it = idx[row];
        float x = emb[it * DIM + lane] * aw[lane];
        x = wave_sum(x);
        if (lane == 0) out[row] = 1.0f / (1.0f + __expf(-(x + ab[0])));
    }
}

// Blocks [0,1024): MFMA Gram + fused exp-sum into S (m_i == 1/T analytically),
//   LDS-reduced across the block's 4 waves -> 64 atomics/block.
// Blocks [1024,1074): class gather for c = b-1024 (featB-only, independent):
//   g_c = sum_{i in c} feat_i, cnt_c; writes
//   T1[c] = (|g_c|^2 - (1+C)*cnt)*INV_T/(C+1e-6), wgt[c] = C/(C+1e-6) (0 if C<1).
__global__ __launch_bounds__(256) void gram_gather(
    const bf16_t* __restrict__ featB, const int* __restrict__ labels,
    float* __restrict__ S, float* __restrict__ T1, float* __restrict__ wgt) {
    __shared__ float sh[4][64];
    __shared__ float sc4[4];
    int b = blockIdx.x;
    int t = threadIdx.x, lane = t & 63, wv = t >> 6;

    if (b < GRAM_BLOCKS) {
        const float scale = INV_T * LOG2E;
        const float bias = -INV_T * LOG2E;
        int col = lane & 31, half = lane >> 5;
        int i0 = (b >> 3) * 64;
        int ig0 = i0 + col, ig1 = i0 + 32 + col;

        // B frags for the two i-groups (identical addressing to A — Gram matrix)
        bf16x8 bf0[4], bf1[4];
        const bf16_t* b0p = featB + (size_t)ig0 * DIM + half * 8;
        const bf16_t* b1p = featB + (size_t)ig1 * DIM + half * 8;
        #pragma unroll
        for (int s = 0; s < 4; ++s) {
            bf0[s] = *reinterpret_cast<const bf16x8*>(b0p + s * 16);
            bf1[s] = *reinterpret_cast<const bf16x8*>(b1p + s * 16);
        }

        int jbase = ((b & 7) * WPB + wv) * JR;
        int rowoff = half * 4;
        float p0[4] = {0.f, 0.f, 0.f, 0.f}, p1[4] = {0.f, 0.f, 0.f, 0.f};

        for (int tile = 0; tile < NTILES; ++tile) {
            int jt = jbase + tile * 32;
            const bf16_t* arowp = featB + (size_t)(jt + col) * DIM + half * 8;
            f32x16 c0 = {}, c1 = {};
            #pragma unroll
            for (int s = 0; s < 4; ++s) {
                bf16x8 a = *reinterpret_cast<const bf16x8*>(arowp + s * 16);
                c0 = __builtin_amdgcn_mfma_f32_32x32x16_bf16(a, bf0[s], c0, 0, 0, 0);
                c1 = __builtin_amdgcn_mfma_f32_32x32x16_bf16(a, bf1[s], c1, 0, 0, 0);
            }
            if (jt != i0) {
                #pragma unroll
                for (int r = 0; r < 16; ++r)
                    p0[r & 3] += EXP2(fmaf(c0[r], scale, bias));
            } else {
                #pragma unroll
                for (int r = 0; r < 16; ++r) {
                    int jrow = (r & 3) + 8 * (r >> 2) + rowoff;
                    float e = EXP2(fmaf(c0[r], scale, bias));
                    p0[r & 3] += (jrow != col) ? e : 0.f;
                }
            }
            if (jt != i0 + 32) {
                #pragma unroll
                for (int r = 0; r < 16; ++r)
                    p1[r & 3] += EXP2(fmaf(c1[r], scale, bias));
            } else {
                #pragma unroll
                for (int r = 0; r < 16; ++r) {
                    int jrow = (r & 3) + 8 * (r >> 2) + rowoff;
                    float e = EXP2(fmaf(c1[r], scale, bias));
                    p1[r & 3] += (jrow != col) ? e : 0.f;
                }
            }
        }
        float a0 = (p0[0] + p0[1]) + (p0[2] + p0[3]);
        float a1 = (p1[0] + p1[1]) + (p1[2] + p1[3]);
        a0 += __shfl_xor(a0, 32, 64);   // full i-tile0 sum, all lanes
        a1 += __shfl_xor(a1, 32, 64);
        // rs[wv][lane] is this wave's contribution to S[i0+lane]
        sh[wv][lane] = (lane < 32) ? a0 : a1;
        __syncthreads();
        if (wv == 0) {
            float s = (sh[0][lane] + sh[1][lane]) + (sh[2][lane] + sh[3][lane]);
            unsafeAtomicAdd(&S[i0 + lane], s);
        }
    } else {
        int c = b - GRAM_BLOCKS;
        float gacc = 0.f, cacc = 0.f;
        for (int strip = wv; strip < N_ITEMS / 64; strip += 4) {
            int r = strip * 64 + lane;
            bool match = (labels[r] == c);
            unsigned long long mask = __ballot(match);
            cacc += match ? 1.f : 0.f;
            const bf16_t* base = featB + (size_t)strip * 64 * DIM + lane;
            while (mask) {
                int bit = __builtin_ctzll(mask);
                mask &= mask - 1;
                gacc += (float)base[bit * DIM];   // 128B coalesced row load
            }
        }
        cacc = wave_sum(cacc);
        sh[wv][lane] = gacc;
        if (lane == 0) sc4[wv] = cacc;
        __syncthreads();
        if (wv == 0) {
            float g = (sh[0][lane] + sh[1][lane]) + (sh[2][lane] + sh[3][lane]);
            float dot = wave_sum(g * g);
            if (lane == 0) {
                float cnt = (sc4[0] + sc4[1]) + (sc4[2] + sc4[3]);
                float C = cnt - 1.f;
                bool ok = (C > 0.5f);
                T1[c]  = ok ? (dot - (1.f + C) * cnt) * INV_T / (C + 1e-6f) : 0.f;
                wgt[c] = ok ? C / (C + 1e-6f) : 0.f;
            }
        }
    }
}

// loss = (1/N) * [ sum_i wgt[l_i]*log(S_i+1e-6)  -  sum_c T1_c ]
// 32 blocks x 256, one row per thread; block 0 wave 0 folds in -sum(T1).
__global__ __launch_bounds__(256) void finalize_k(
    const float* __restrict__ S, const int* __restrict__ labels,
    const float* __restrict__ T1, const float* __restrict__ wgt,
    float* __restrict__ out_loss) {
    __shared__ float red[4];
    int t = threadIdx.x, lane = t & 63, wv = t >> 6;
    int r = blockIdx.x * 256 + t;
    float acc = wgt[labels[r]] * __logf(S[r] + 1e-6f);
    float v = wave_sum(acc);
    float t1s = 0.f;
    if (blockIdx.x == 0 && wv == 0) {
        float t1v = (lane < NCLASS) ? T1[lane] : 0.f;
        t1s = wave_sum(t1v);
    }
    if (lane == 0) red[wv] = v;
    __syncthreads();
    if (t == 0) {
        float s = (red[0] + red[1]) + (red[2] + red[3]);
        s -= t1s;   // nonzero only in block 0
        unsafeAtomicAdd(out_loss, s / (float)N_ITEMS);
    }
}

extern "C" void kernel_launch(void* const* d_in, const int* in_sizes, int n_in,
                              void* d_out, int out_size, void* d_ws, size_t ws_size,
                              hipStream_t stream) {
    const int*   item_indices = (const int*)d_in[0];
    const int*   labels       = (const int*)d_in[1];
    const float* emb          = (const float*)d_in[2];
    const float* aw           = (const float*)d_in[3];
    const float* ab           = (const float*)d_in[4];
    float* out = (float*)d_out;   // [4096 ratings][1 supcon]

    bf16_t* featB = (bf16_t*)d_ws;                       // 8192*64 bf16 (1 MB)
    float*  S     = (float*)(featB + N_ITEMS * DIM);     // 8192
    float*  T1    = S + N_ITEMS;                         // 50
    float*  wgt   = T1 + NCLASS;                         // 50

    prep_rating<<<N_ITEMS / 4 + BATCH / 4, 256, 0, stream>>>(
        emb, item_indices, aw, ab, featB, S, out);

    gram_gather<<<GRAM_BLOCKS + NCLASS, 256, 0, stream>>>(
        featB, labels, S, T1, wgt);

    finalize_k<<<N_ITEMS / 256, 256, 0, stream>>>(S, labels, T1, wgt,
                                                  out + BATCH);
}